// Round 14
// baseline (107.509 us; speedup 1.0000x reference)
//
#include <hip/hip_runtime.h>

#define SLOPE 0.01f

typedef __attribute__((ext_vector_type(8))) short short8;
typedef __attribute__((ext_vector_type(4))) float f32x4;

__device__ __forceinline__ float lrelu(float v) { return v >= 0.f ? v : SLOPE * v; }

__device__ __forceinline__ unsigned short f2bf(float f) {
    union { float f; unsigned int u; } v; v.f = f;
    unsigned int r = v.u + 0x7fffu + ((v.u >> 16) & 1u);
    return (unsigned short)(r >> 16);
}
__device__ __forceinline__ float bf2f(unsigned short h) {
    union { unsigned int u; float f; } v; v.u = ((unsigned int)h) << 16;
    return v.f;
}
__device__ __forceinline__ unsigned short bfmax4(unsigned short a, unsigned short b,
                                                 unsigned short c, unsigned short d) {
    float m = fmaxf(fmaxf(bf2f(a), bf2f(b)), fmaxf(bf2f(c), bf2f(d)));
    union { float f; unsigned int u; } v; v.f = m;
    return (unsigned short)(v.u >> 16);
}
__device__ __forceinline__ unsigned long long pk4(unsigned short a, unsigned short b,
                                                  unsigned short c, unsigned short d) {
    return (unsigned long long)a | ((unsigned long long)b << 16)
         | ((unsigned long long)c << 32) | ((unsigned long long)d << 48);
}

// MFMA A-fragment swizzle (16-oc tiles):
//   frag for (octile t, kblock kb) at lane l = W[((t*(K/32)+kb)*64+l)*8 .. +8)
__device__ __forceinline__ int swz(int oc, int k, int Kdiv32) {
    return (((oc >> 4) * Kdiv32 + (k >> 5)) * 64 + ((k >> 3) & 3) * 16 + (oc & 15)) * 8 + (k & 7);
}

// ---------------------------------------------------------------------------
// 3 kernels / 2 boundaries (R13 structure, best known 67us).
// R14 changes: k_front 2018x256 -> 256x512 grid-stride (48MB->9.8MB weight
// staging, shorter dispatch ramp); k_conv2 168x256 -> 84x512 (2 waves/SIMD
// latency hiding; R12-validated gw mapping). k_tail unchanged.
// Workspace (f32 slot offsets):
//   P2   bf16 [4][25][25][128]   @ 0       (160000)
//   Z2   bf16 [4][21][21][128]   @ 160000  (112896)
//   W2s  bf16 swz K=3200         @ 272896  (204800)
//   W3s  bf16 swz K=3200         @ 477696  (204800)
//   C4Bs bf16 swz K=128          @ 682496  (16384)
//   C5Bs bf16 swz K=256          @ 698880  (16384)
//   DWBs bf16 swz K=128          @ 715264  (32768)
// ---------------------------------------------------------------------------

// K1: 256 blocks x 512 threads. Per block: conv1+pool1 slice (weights staged
// once), one W2/W3 oc-row swizzle-transpose, 512 swizzled tail-weight casts.
__global__ __launch_bounds__(512) void k_front(const float* __restrict__ x,
                                               const float* __restrict__ c1w,
                                               const float* __restrict__ c1b,
                                               const float* __restrict__ c2w,
                                               const float* __restrict__ c3w,
                                               const float* __restrict__ c4w,
                                               const float* __restrict__ c5w,
                                               const float* __restrict__ dw,
                                               unsigned* __restrict__ P2u,
                                               unsigned short* __restrict__ W2s,
                                               unsigned short* __restrict__ W3s,
                                               unsigned short* __restrict__ C4Bs,
                                               unsigned short* __restrict__ C5Bs,
                                               unsigned short* __restrict__ DWBs) {
    __shared__ float smem[9600];
    const int tid = threadIdx.x;
    const int bid = blockIdx.x;

    // ---- conv1+pool1 -> P2 (u32-packed pairs, 625 per block) ----
    for (int idx = tid; idx < 9600; idx += 512) smem[idx] = c1w[idx];
    __syncthreads();
    for (int q = tid; q < 625; q += 512) {
        int t32 = bid * 625 + q;          // [0, 160000)
        int icp = t32 & 63;
        int rest = t32 >> 6;
        int B = rest % 25;
        int A = (rest / 25) % 25;
        int ph = rest / 625;
        int py = ph >> 1, px = ph & 1;
        int r0 = 2 * A + py, s0 = 2 * B + px;
        unsigned packed = 0;
#pragma unroll
        for (int ii = 0; ii < 2; ++ii) {
            int ic = icp * 2 + ii;
            float a00 = 0.f, a01 = 0.f, a10 = 0.f, a11 = 0.f;
            const float* lw = smem + ic * 75;
            for (int c = 0; c < 3; ++c) {
                const float* xc = x + c * 576;
                const float* lwc = lw + c * 25;
#pragma unroll
                for (int ky = 0; ky < 5; ++ky) {
                    int iy = r0 + ky - 16;
                    bool v0 = (iy >= 0) && (iy < 24);
                    bool v1 = (iy + 1 >= 0) && (iy + 1 < 24);
                    if (!v0 && !v1) continue;
#pragma unroll
                    for (int kx = 0; kx < 5; ++kx) {
                        int ix = s0 + kx - 16;
                        float w = lwc[ky * 5 + kx];
                        bool u0 = (ix >= 0) && (ix < 24);
                        bool u1 = (ix + 1 >= 0) && (ix + 1 < 24);
                        float x00 = (v0 && u0) ? xc[iy * 24 + ix] : 0.f;
                        float x01 = (v0 && u1) ? xc[iy * 24 + ix + 1] : 0.f;
                        float x10 = (v1 && u0) ? xc[(iy + 1) * 24 + ix] : 0.f;
                        float x11 = (v1 && u1) ? xc[(iy + 1) * 24 + ix + 1] : 0.f;
                        a00 += x00 * w; a01 += x01 * w; a10 += x10 * w; a11 += x11 * w;
                    }
                }
            }
            float mx = fmaxf(fmaxf(a00, a01), fmaxf(a10, a11));
            unsigned short r = f2bf(lrelu(c1b[ic] + mx));
            packed |= ((unsigned)r) << (16 * ii);
        }
        P2u[t32] = packed;
    }

    // ---- W2/W3 swizzle-transpose: one oc-row per block ----
    {
        int oc = bid & 127;
        const float* src = (bid < 128) ? (c2w + oc * 3200) : (c3w + oc * 3200);
        unsigned short* dst = (bid < 128) ? W2s : W3s;
        __syncthreads();
        for (int idx = tid; idx < 3200; idx += 512) smem[idx] = src[idx];
        __syncthreads();
        for (int g = tid; g < 800; g += 512) {
            int ic0 = (g & 31) * 4;
            int kpos = g >> 5;
            unsigned long long v = pk4(f2bf(smem[(ic0 + 0) * 25 + kpos]),
                                       f2bf(smem[(ic0 + 1) * 25 + kpos]),
                                       f2bf(smem[(ic0 + 2) * 25 + kpos]),
                                       f2bf(smem[(ic0 + 3) * 25 + kpos]));
            *(unsigned long long*)(dst + swz(oc, kpos * 128 + ic0, 100)) = v;
        }
    }

    // ---- swizzled bf16 casts of c4w/c5w/dw (u64 each, tid<128) ----
    if (tid < 128) {
        int e0 = (bid * 128 + tid) * 4;   // [0, 131072)
        if (e0 < 32768) {
            int oc = e0 >> 7, k = e0 & 127;
            *(unsigned long long*)(C4Bs + swz(oc, k, 4)) =
                pk4(f2bf(c4w[e0]), f2bf(c4w[e0 + 1]), f2bf(c4w[e0 + 2]), f2bf(c4w[e0 + 3]));
        } else if (e0 < 65536) {
            int e2 = e0 - 32768;
            int oc = e2 >> 8, k = e2 & 255;
            *(unsigned long long*)(C5Bs + swz(oc, k, 8)) =
                pk4(f2bf(c5w[e2]), f2bf(c5w[e2 + 1]), f2bf(c5w[e2 + 2]), f2bf(c5w[e2 + 3]));
        } else {
            int e2 = e0 - 65536;
            int oc = e2 >> 7, k = e2 & 127;
            *(unsigned long long*)(DWBs + swz(oc, k, 4)) =
                pk4(f2bf(dw[e2]), f2bf(dw[e2 + 1]), f2bf(dw[e2 + 2]), f2bf(dw[e2 + 3]));
        }
    }
}

// K2: conv2 via MFMA. 84 blocks x 512 threads (8 waves, 2/SIMD);
// gw = bid*8+wid covers exactly 672 wave-units (R12-validated mapping).
__global__ __launch_bounds__(512) void k_conv2(const unsigned short* __restrict__ P2,
                                               const unsigned short* __restrict__ W2s,
                                               const float* __restrict__ bias,
                                               unsigned short* __restrict__ Z2) {
    int tid = threadIdx.x, lane = tid & 63, wid = tid >> 6;
    int gw = blockIdx.x * 8 + wid;        // [0, 672)
    int ph = gw / 168;
    int rem = gw % 168;
    int A = rem / 8;
    int t = rem % 8;
    int m = lane & 15, bq = lane >> 4;
    const unsigned short* wbase = W2s + (t * 6400 + lane) * 8;
    const unsigned short* pbase = P2 + ((ph * 25 + A) * 25) * 128 + 8 * bq;
    f32x4 acc0 = {0.f, 0.f, 0.f, 0.f}, acc1 = {0.f, 0.f, 0.f, 0.f};
    for (int kpos = 0; kpos < 25; ++kpos) {
        int ky = kpos / 5, kx = kpos % 5;
        const unsigned short* wp = wbase + kpos * 2048;
        const unsigned short* p0 = pbase + (ky * 25 + m + kx) * 128;
        const unsigned short* p1 = p0 + 5 * 128;
#pragma unroll
        for (int cc = 0; cc < 4; ++cc) {
            short8 a  = *(const short8*)(wp + cc * 512);
            short8 b0 = *(const short8*)(p0 + cc * 32);
            short8 b1 = *(const short8*)(p1 + cc * 32);
            acc0 = __builtin_amdgcn_mfma_f32_16x16x32_bf16(a, b0, acc0, 0, 0, 0);
            acc1 = __builtin_amdgcn_mfma_f32_16x16x32_bf16(a, b1, acc1, 0, 0, 0);
        }
    }
    int ocb = t * 16 + 4 * bq;
    float b0v = bias[ocb], b1v = bias[ocb + 1], b2v = bias[ocb + 2], b3v = bias[ocb + 3];
    unsigned short* zrow = Z2 + ((ph * 21 + A) * 21) * 128 + ocb;
    {
        ushort4 pk;
        pk.x = f2bf(lrelu(acc0.x + b0v));
        pk.y = f2bf(lrelu(acc0.y + b1v));
        pk.z = f2bf(lrelu(acc0.z + b2v));
        pk.w = f2bf(lrelu(acc0.w + b3v));
        *(ushort4*)(zrow + m * 128) = pk;          // B = m (0..15)
    }
    if (m >= 11) {                                 // B = m+5 (16..20)
        ushort4 pk;
        pk.x = f2bf(lrelu(acc1.x + b0v));
        pk.y = f2bf(lrelu(acc1.y + b1v));
        pk.z = f2bf(lrelu(acc1.z + b2v));
        pk.w = f2bf(lrelu(acc1.w + b3v));
        *(ushort4*)(zrow + (m + 5) * 128) = pk;
    }
}

// K3: pool2-gather + conv3 + conv4 + conv5 + dense (R13-exact).
// 36 blocks x 512 threads (8 waves), 16 patches per block, LDS 119.8 KB.
#define QSTR 3208
__global__ __launch_bounds__(512) void k_tail(const unsigned short* __restrict__ Z2,
                                              const unsigned short* __restrict__ W3s,
                                              const float* __restrict__ c3b,
                                              const unsigned short* __restrict__ C4Bs,
                                              const float* __restrict__ c4b,
                                              const unsigned short* __restrict__ C5Bs,
                                              const float* __restrict__ c5b,
                                              const unsigned short* __restrict__ DWBs,
                                              const float* __restrict__ db,
                                              float* __restrict__ out) {
    __shared__ unsigned short lds[59904];          // Qw | h3 | h4 | h5
    unsigned short* Qw   = lds;                    // [16][QSTR]
    unsigned short* h3bf = lds + 16 * QSTR;        // [16][136]
    unsigned short* h4bf = h3bf + 16 * 136;        // [16][264]
    unsigned short* h5bf = h4bf + 16 * 264;        // [16][136]

    int bid = blockIdx.x, tid = threadIdx.x;
    int n0 = bid * 16;
    int lane = tid & 63, w = tid >> 6;             // 8 waves
    int m = lane & 15, bq = lane >> 4;

    // ---- pool2 gather: window[p][kpos*128+ic] = max 2x2 of Z2 ----
    for (int v = tid; v < 6400; v += 512) {
        int p = v / 400;
        int rem = v - p * 400;
        int kpos = rem >> 4;
        int ic0 = (rem & 15) * 8;
        int e = kpos / 5, f = kpos % 5;
        int n = n0 + p, i = n / 24, j = n % 24;
        int ph1 = (i & 1) * 2 + (j & 1);
        int C = (i >> 2) + e, D = (j >> 2) + f;
        int r0 = 2 * C + ((i >> 1) & 1), s0 = 2 * D + ((j >> 1) & 1);
        const unsigned short* z = Z2 + ((ph1 * 21 + r0) * 21 + s0) * 128 + ic0;
        ushort4 za0 = *(const ushort4*)(z);
        ushort4 za1 = *(const ushort4*)(z + 4);
        ushort4 zb0 = *(const ushort4*)(z + 128);
        ushort4 zb1 = *(const ushort4*)(z + 132);
        ushort4 zc0 = *(const ushort4*)(z + 21 * 128);
        ushort4 zc1 = *(const ushort4*)(z + 21 * 128 + 4);
        ushort4 zd0 = *(const ushort4*)(z + 22 * 128);
        ushort4 zd1 = *(const ushort4*)(z + 22 * 128 + 4);
        ushort4 r0v, r1v;
        r0v.x = bfmax4(za0.x, zb0.x, zc0.x, zd0.x);
        r0v.y = bfmax4(za0.y, zb0.y, zc0.y, zd0.y);
        r0v.z = bfmax4(za0.z, zb0.z, zc0.z, zd0.z);
        r0v.w = bfmax4(za0.w, zb0.w, zc0.w, zd0.w);
        r1v.x = bfmax4(za1.x, zb1.x, zc1.x, zd1.x);
        r1v.y = bfmax4(za1.y, zb1.y, zc1.y, zd1.y);
        r1v.z = bfmax4(za1.z, zb1.z, zc1.z, zd1.z);
        r1v.w = bfmax4(za1.w, zb1.w, zc1.w, zd1.w);
        unsigned short* dst = Qw + p * QSTR + rem * 8;
        *(ushort4*)(dst) = r0v;
        *(ushort4*)(dst + 4) = r1v;
    }
    __syncthreads();

    // ---- conv3: octile w per wave; B from LDS ----
    {
        const unsigned short* qb = Qw + m * QSTR + 8 * bq;
        const unsigned short* wbase = W3s + (w * 6400 + lane) * 8;
        f32x4 acc = {0.f, 0.f, 0.f, 0.f};
        for (int kpos = 0; kpos < 25; ++kpos) {
            const unsigned short* qp = qb + kpos * 128;
            const unsigned short* wp = wbase + kpos * 2048;
#pragma unroll
            for (int cc = 0; cc < 4; ++cc) {
                short8 a = *(const short8*)(wp + cc * 512);
                short8 b = *(const short8*)(qp + cc * 32);
                acc = __builtin_amdgcn_mfma_f32_16x16x32_bf16(a, b, acc, 0, 0, 0);
            }
        }
        int oc = w * 16 + bq * 4;
        uint2 pk;
        pk.x = (unsigned)f2bf(lrelu(acc.x + c3b[oc])) | ((unsigned)f2bf(lrelu(acc.y + c3b[oc + 1])) << 16);
        pk.y = (unsigned)f2bf(lrelu(acc.z + c3b[oc + 2])) | ((unsigned)f2bf(lrelu(acc.w + c3b[oc + 3])) << 16);
        *(uint2*)(&h3bf[m * 136 + oc]) = pk;
    }
    __syncthreads();

    // ---- conv4: octiles {w*2, w*2+1}, K=128 ----
    {
        f32x4 acc[2] = {{0,0,0,0},{0,0,0,0}};
#pragma unroll
        for (int t = 0; t < 2; ++t) {
            const unsigned short* abase = C4Bs + ((w * 2 + t) * 4 * 64 + lane) * 8;
#pragma unroll
            for (int cc = 0; cc < 4; ++cc) {
                short8 a = *(const short8*)(abase + cc * 512);
                short8 b = *(const short8*)(&h3bf[m * 136 + cc * 32 + 8 * bq]);
                acc[t] = __builtin_amdgcn_mfma_f32_16x16x32_bf16(a, b, acc[t], 0, 0, 0);
            }
        }
#pragma unroll
        for (int t = 0; t < 2; ++t) {
            int oc = (w * 2 + t) * 16 + bq * 4;
            uint2 pk;
            pk.x = (unsigned)f2bf(lrelu(acc[t].x + c4b[oc])) | ((unsigned)f2bf(lrelu(acc[t].y + c4b[oc + 1])) << 16);
            pk.y = (unsigned)f2bf(lrelu(acc[t].z + c4b[oc + 2])) | ((unsigned)f2bf(lrelu(acc[t].w + c4b[oc + 3])) << 16);
            *(uint2*)(&h4bf[m * 264 + oc]) = pk;
        }
    }
    __syncthreads();

    // ---- conv5: octile w, K=256 ----
    {
        const unsigned short* abase = C5Bs + (w * 8 * 64 + lane) * 8;
        f32x4 acc = {0.f, 0.f, 0.f, 0.f};
#pragma unroll
        for (int cc = 0; cc < 8; ++cc) {
            short8 a = *(const short8*)(abase + cc * 512);
            short8 b = *(const short8*)(&h4bf[m * 264 + cc * 32 + 8 * bq]);
            acc = __builtin_amdgcn_mfma_f32_16x16x32_bf16(a, b, acc, 0, 0, 0);
        }
        int oc = w * 16 + bq * 4;
        uint2 pk;
        pk.x = (unsigned)f2bf(lrelu(acc.x + c5b[oc])) | ((unsigned)f2bf(lrelu(acc.y + c5b[oc + 1])) << 16);
        pk.y = (unsigned)f2bf(lrelu(acc.z + c5b[oc + 2])) | ((unsigned)f2bf(lrelu(acc.w + c5b[oc + 3])) << 16);
        *(uint2*)(&h5bf[m * 136 + oc]) = pk;
    }
    __syncthreads();

    // ---- dense: octiles w*4..w*4+3, K=128 ----
    {
        f32x4 acc[4] = {{0,0,0,0},{0,0,0,0},{0,0,0,0},{0,0,0,0}};
#pragma unroll
        for (int t = 0; t < 4; ++t) {
            const unsigned short* abase = DWBs + ((w * 4 + t) * 4 * 64 + lane) * 8;
#pragma unroll
            for (int cc = 0; cc < 4; ++cc) {
                short8 a = *(const short8*)(abase + cc * 512);
                short8 b = *(const short8*)(&h5bf[m * 136 + cc * 32 + 8 * bq]);
                acc[t] = __builtin_amdgcn_mfma_f32_16x16x32_bf16(a, b, acc[t], 0, 0, 0);
            }
        }
#pragma unroll
        for (int t = 0; t < 4; ++t) {
            int oc = (w * 4 + t) * 16 + bq * 4;
            out[(oc + 0) * 576 + n0 + m] = acc[t].x + db[oc + 0];
            out[(oc + 1) * 576 + n0 + m] = acc[t].y + db[oc + 1];
            out[(oc + 2) * 576 + n0 + m] = acc[t].z + db[oc + 2];
            out[(oc + 3) * 576 + n0 + m] = acc[t].w + db[oc + 3];
        }
    }
}

extern "C" void kernel_launch(void* const* d_in, const int* in_sizes, int n_in,
                              void* d_out, int out_size, void* d_ws, size_t ws_size,
                              hipStream_t stream) {
    const float* x   = (const float*)d_in[0];
    const float* c1w = (const float*)d_in[1];
    const float* c1b = (const float*)d_in[2];
    const float* c2w = (const float*)d_in[3];
    const float* c2b = (const float*)d_in[4];
    const float* c3w = (const float*)d_in[5];
    const float* c3b = (const float*)d_in[6];
    const float* c4w = (const float*)d_in[7];
    const float* c4b = (const float*)d_in[8];
    const float* c5w = (const float*)d_in[9];
    const float* c5b = (const float*)d_in[10];
    const float* dw  = (const float*)d_in[11];
    const float* db  = (const float*)d_in[12];
    float* out = (float*)d_out;

    float* ws = (float*)d_ws;
    unsigned*       P2u  = (unsigned*)(ws);                  // 160000 f32 slots
    unsigned short* P2   = (unsigned short*)(ws);
    unsigned short* Z2   = (unsigned short*)(ws + 160000);   // 112896
    unsigned short* W2s  = (unsigned short*)(ws + 272896);   // 204800
    unsigned short* W3s  = (unsigned short*)(ws + 477696);   // 204800
    unsigned short* C4Bs = (unsigned short*)(ws + 682496);   // 16384
    unsigned short* C5Bs = (unsigned short*)(ws + 698880);   // 16384
    unsigned short* DWBs = (unsigned short*)(ws + 715264);   // 32768

    k_front<<<256, 512, 0, stream>>>(x, c1w, c1b, c2w, c3w, c4w, c5w, dw,
                                     P2u, W2s, W3s, C4Bs, C5Bs, DWBs);
    k_conv2<<<84, 512, 0, stream>>>(P2, W2s, c2b, Z2);
    k_tail<<<36, 512, 0, stream>>>(Z2, W3s, c3b, C4Bs, c4b, C5Bs, c5b, DWBs, db, out);
}

// Round 15
// 82.353 us; speedup vs baseline: 1.3055x; 1.3055x over previous
//
#include <hip/hip_runtime.h>

#define SLOPE 0.01f

typedef __attribute__((ext_vector_type(8))) short short8;
typedef __attribute__((ext_vector_type(4))) float f32x4;

__device__ __forceinline__ float lrelu(float v) { return v >= 0.f ? v : SLOPE * v; }

__device__ __forceinline__ unsigned short f2bf(float f) {
    union { float f; unsigned int u; } v; v.f = f;
    unsigned int r = v.u + 0x7fffu + ((v.u >> 16) & 1u);
    return (unsigned short)(r >> 16);
}
__device__ __forceinline__ float bf2f(unsigned short h) {
    union { unsigned int u; float f; } v; v.u = ((unsigned int)h) << 16;
    return v.f;
}
__device__ __forceinline__ unsigned short bfmax4(unsigned short a, unsigned short b,
                                                 unsigned short c, unsigned short d) {
    float m = fmaxf(fmaxf(bf2f(a), bf2f(b)), fmaxf(bf2f(c), bf2f(d)));
    union { float f; unsigned int u; } v; v.f = m;
    return (unsigned short)(v.u >> 16);
}
__device__ __forceinline__ unsigned long long pk4(unsigned short a, unsigned short b,
                                                  unsigned short c, unsigned short d) {
    return (unsigned long long)a | ((unsigned long long)b << 16)
         | ((unsigned long long)c << 32) | ((unsigned long long)d << 48);
}

// MFMA A-fragment swizzle (16-oc tiles):
//   frag for (octile t, kblock kb) at lane l = W[((t*(K/32)+kb)*64+l)*8 .. +8)
__device__ __forceinline__ int swz(int oc, int k, int Kdiv32) {
    return (((oc >> 4) * Kdiv32 + (k >> 5)) * 64 + ((k >> 3) & 3) * 16 + (oc & 15)) * 8 + (k & 7);
}

// ---------------------------------------------------------------------------
// R15 = R13 (67us best) with only k_front replaced by the R14 256x512 version.
// R14's k_conv2@84x512 regressed (compiled at 36 VGPR -> no load pipelining ->
// 51us latency chain); reverted to the R13-exact 168x256 kernel (88 VGPR).
// Workspace (f32 slot offsets):
//   P2   bf16 [4][25][25][128]   @ 0       (160000)
//   Z2   bf16 [4][21][21][128]   @ 160000  (112896)
//   W2s  bf16 swz K=3200         @ 272896  (204800)
//   W3s  bf16 swz K=3200         @ 477696  (204800)
//   C4Bs bf16 swz K=128          @ 682496  (16384)
//   C5Bs bf16 swz K=256          @ 698880  (16384)
//   DWBs bf16 swz K=128          @ 715264  (32768)
// ---------------------------------------------------------------------------

// K1: 256 blocks x 512 threads (R14-validated-structure; staging 9.8MB).
__global__ __launch_bounds__(512) void k_front(const float* __restrict__ x,
                                               const float* __restrict__ c1w,
                                               const float* __restrict__ c1b,
                                               const float* __restrict__ c2w,
                                               const float* __restrict__ c3w,
                                               const float* __restrict__ c4w,
                                               const float* __restrict__ c5w,
                                               const float* __restrict__ dw,
                                               unsigned* __restrict__ P2u,
                                               unsigned short* __restrict__ W2s,
                                               unsigned short* __restrict__ W3s,
                                               unsigned short* __restrict__ C4Bs,
                                               unsigned short* __restrict__ C5Bs,
                                               unsigned short* __restrict__ DWBs) {
    __shared__ float smem[9600];
    const int tid = threadIdx.x;
    const int bid = blockIdx.x;

    // ---- conv1+pool1 -> P2 (u32-packed pairs, 625 per block) ----
    for (int idx = tid; idx < 9600; idx += 512) smem[idx] = c1w[idx];
    __syncthreads();
    for (int q = tid; q < 625; q += 512) {
        int t32 = bid * 625 + q;          // [0, 160000)
        int icp = t32 & 63;
        int rest = t32 >> 6;
        int B = rest % 25;
        int A = (rest / 25) % 25;
        int ph = rest / 625;
        int py = ph >> 1, px = ph & 1;
        int r0 = 2 * A + py, s0 = 2 * B + px;
        unsigned packed = 0;
#pragma unroll
        for (int ii = 0; ii < 2; ++ii) {
            int ic = icp * 2 + ii;
            float a00 = 0.f, a01 = 0.f, a10 = 0.f, a11 = 0.f;
            const float* lw = smem + ic * 75;
            for (int c = 0; c < 3; ++c) {
                const float* xc = x + c * 576;
                const float* lwc = lw + c * 25;
#pragma unroll
                for (int ky = 0; ky < 5; ++ky) {
                    int iy = r0 + ky - 16;
                    bool v0 = (iy >= 0) && (iy < 24);
                    bool v1 = (iy + 1 >= 0) && (iy + 1 < 24);
                    if (!v0 && !v1) continue;
#pragma unroll
                    for (int kx = 0; kx < 5; ++kx) {
                        int ix = s0 + kx - 16;
                        float w = lwc[ky * 5 + kx];
                        bool u0 = (ix >= 0) && (ix < 24);
                        bool u1 = (ix + 1 >= 0) && (ix + 1 < 24);
                        float x00 = (v0 && u0) ? xc[iy * 24 + ix] : 0.f;
                        float x01 = (v0 && u1) ? xc[iy * 24 + ix + 1] : 0.f;
                        float x10 = (v1 && u0) ? xc[(iy + 1) * 24 + ix] : 0.f;
                        float x11 = (v1 && u1) ? xc[(iy + 1) * 24 + ix + 1] : 0.f;
                        a00 += x00 * w; a01 += x01 * w; a10 += x10 * w; a11 += x11 * w;
                    }
                }
            }
            float mx = fmaxf(fmaxf(a00, a01), fmaxf(a10, a11));
            unsigned short r = f2bf(lrelu(c1b[ic] + mx));
            packed |= ((unsigned)r) << (16 * ii);
        }
        P2u[t32] = packed;
    }

    // ---- W2/W3 swizzle-transpose: one oc-row per block ----
    {
        int oc = bid & 127;
        const float* src = (bid < 128) ? (c2w + oc * 3200) : (c3w + oc * 3200);
        unsigned short* dst = (bid < 128) ? W2s : W3s;
        __syncthreads();
        for (int idx = tid; idx < 3200; idx += 512) smem[idx] = src[idx];
        __syncthreads();
        for (int g = tid; g < 800; g += 512) {
            int ic0 = (g & 31) * 4;
            int kpos = g >> 5;
            unsigned long long v = pk4(f2bf(smem[(ic0 + 0) * 25 + kpos]),
                                       f2bf(smem[(ic0 + 1) * 25 + kpos]),
                                       f2bf(smem[(ic0 + 2) * 25 + kpos]),
                                       f2bf(smem[(ic0 + 3) * 25 + kpos]));
            *(unsigned long long*)(dst + swz(oc, kpos * 128 + ic0, 100)) = v;
        }
    }

    // ---- swizzled bf16 casts of c4w/c5w/dw (u64 each, tid<128) ----
    if (tid < 128) {
        int e0 = (bid * 128 + tid) * 4;   // [0, 131072)
        if (e0 < 32768) {
            int oc = e0 >> 7, k = e0 & 127;
            *(unsigned long long*)(C4Bs + swz(oc, k, 4)) =
                pk4(f2bf(c4w[e0]), f2bf(c4w[e0 + 1]), f2bf(c4w[e0 + 2]), f2bf(c4w[e0 + 3]));
        } else if (e0 < 65536) {
            int e2 = e0 - 32768;
            int oc = e2 >> 8, k = e2 & 255;
            *(unsigned long long*)(C5Bs + swz(oc, k, 8)) =
                pk4(f2bf(c5w[e2]), f2bf(c5w[e2 + 1]), f2bf(c5w[e2 + 2]), f2bf(c5w[e2 + 3]));
        } else {
            int e2 = e0 - 65536;
            int oc = e2 >> 7, k = e2 & 127;
            *(unsigned long long*)(DWBs + swz(oc, k, 4)) =
                pk4(f2bf(dw[e2]), f2bf(dw[e2 + 1]), f2bf(dw[e2 + 2]), f2bf(dw[e2 + 3]));
        }
    }
}

// K2: conv2 via MFMA, swizzled W2 -> Z2[ph][A][B][oc]  (R13-EXACT, 168x256)
__global__ __launch_bounds__(256) void k_conv2(const unsigned short* __restrict__ P2,
                                               const unsigned short* __restrict__ W2s,
                                               const float* __restrict__ bias,
                                               unsigned short* __restrict__ Z2) {
    int bid = blockIdx.x;          // 168 = 4ph * 21A * 2oh
    int ph = bid / 42;
    int rem = bid % 42;
    int A = rem >> 1;
    int oh = rem & 1;
    int tid = threadIdx.x, lane = tid & 63, wid = tid >> 6;
    int m = lane & 15, bq = lane >> 4;
    int oc0 = oh * 64 + wid * 16;
    int t = oh * 4 + wid;                      // oc tile index
    const unsigned short* wbase = W2s + (t * 100 * 64 + lane) * 8;
    const unsigned short* pbase = P2 + ((ph * 25 + A) * 25) * 128 + 8 * bq;
    f32x4 acc0 = {0.f, 0.f, 0.f, 0.f}, acc1 = {0.f, 0.f, 0.f, 0.f};
    for (int kpos = 0; kpos < 25; ++kpos) {
        int ky = kpos / 5, kx = kpos % 5;
        const unsigned short* wp = wbase + kpos * 4 * 512;
        const unsigned short* p0 = pbase + (ky * 25 + m + kx) * 128;
        const unsigned short* p1 = p0 + 5 * 128;
#pragma unroll
        for (int cc = 0; cc < 4; ++cc) {
            short8 a  = *(const short8*)(wp + cc * 512);
            short8 b0 = *(const short8*)(p0 + cc * 32);
            short8 b1 = *(const short8*)(p1 + cc * 32);
            acc0 = __builtin_amdgcn_mfma_f32_16x16x32_bf16(a, b0, acc0, 0, 0, 0);
            acc1 = __builtin_amdgcn_mfma_f32_16x16x32_bf16(a, b1, acc1, 0, 0, 0);
        }
    }
    int ocb = oc0 + 4 * bq;
    float b0v = bias[ocb], b1v = bias[ocb + 1], b2v = bias[ocb + 2], b3v = bias[ocb + 3];
    unsigned short* zrow = Z2 + ((ph * 21 + A) * 21) * 128 + ocb;
    {
        ushort4 pk;
        pk.x = f2bf(lrelu(acc0.x + b0v));
        pk.y = f2bf(lrelu(acc0.y + b1v));
        pk.z = f2bf(lrelu(acc0.z + b2v));
        pk.w = f2bf(lrelu(acc0.w + b3v));
        *(ushort4*)(zrow + m * 128) = pk;          // B = m (0..15)
    }
    if (m >= 11) {                                 // B = m+5 (16..20)
        ushort4 pk;
        pk.x = f2bf(lrelu(acc1.x + b0v));
        pk.y = f2bf(lrelu(acc1.y + b1v));
        pk.z = f2bf(lrelu(acc1.z + b2v));
        pk.w = f2bf(lrelu(acc1.w + b3v));
        *(ushort4*)(zrow + (m + 5) * 128) = pk;
    }
}

// K3: pool2-gather + conv3 + conv4 + conv5 + dense (R13-exact).
// 36 blocks x 512 threads (8 waves), 16 patches per block, LDS 119.8 KB.
#define QSTR 3208
__global__ __launch_bounds__(512) void k_tail(const unsigned short* __restrict__ Z2,
                                              const unsigned short* __restrict__ W3s,
                                              const float* __restrict__ c3b,
                                              const unsigned short* __restrict__ C4Bs,
                                              const float* __restrict__ c4b,
                                              const unsigned short* __restrict__ C5Bs,
                                              const float* __restrict__ c5b,
                                              const unsigned short* __restrict__ DWBs,
                                              const float* __restrict__ db,
                                              float* __restrict__ out) {
    __shared__ unsigned short lds[59904];          // Qw | h3 | h4 | h5
    unsigned short* Qw   = lds;                    // [16][QSTR]
    unsigned short* h3bf = lds + 16 * QSTR;        // [16][136]
    unsigned short* h4bf = h3bf + 16 * 136;        // [16][264]
    unsigned short* h5bf = h4bf + 16 * 264;        // [16][136]

    int bid = blockIdx.x, tid = threadIdx.x;
    int n0 = bid * 16;
    int lane = tid & 63, w = tid >> 6;             // 8 waves
    int m = lane & 15, bq = lane >> 4;

    // ---- pool2 gather: window[p][kpos*128+ic] = max 2x2 of Z2 ----
    for (int v = tid; v < 6400; v += 512) {
        int p = v / 400;
        int rem = v - p * 400;
        int kpos = rem >> 4;
        int ic0 = (rem & 15) * 8;
        int e = kpos / 5, f = kpos % 5;
        int n = n0 + p, i = n / 24, j = n % 24;
        int ph1 = (i & 1) * 2 + (j & 1);
        int C = (i >> 2) + e, D = (j >> 2) + f;
        int r0 = 2 * C + ((i >> 1) & 1), s0 = 2 * D + ((j >> 1) & 1);
        const unsigned short* z = Z2 + ((ph1 * 21 + r0) * 21 + s0) * 128 + ic0;
        ushort4 za0 = *(const ushort4*)(z);
        ushort4 za1 = *(const ushort4*)(z + 4);
        ushort4 zb0 = *(const ushort4*)(z + 128);
        ushort4 zb1 = *(const ushort4*)(z + 132);
        ushort4 zc0 = *(const ushort4*)(z + 21 * 128);
        ushort4 zc1 = *(const ushort4*)(z + 21 * 128 + 4);
        ushort4 zd0 = *(const ushort4*)(z + 22 * 128);
        ushort4 zd1 = *(const ushort4*)(z + 22 * 128 + 4);
        ushort4 r0v, r1v;
        r0v.x = bfmax4(za0.x, zb0.x, zc0.x, zd0.x);
        r0v.y = bfmax4(za0.y, zb0.y, zc0.y, zd0.y);
        r0v.z = bfmax4(za0.z, zb0.z, zc0.z, zd0.z);
        r0v.w = bfmax4(za0.w, zb0.w, zc0.w, zd0.w);
        r1v.x = bfmax4(za1.x, zb1.x, zc1.x, zd1.x);
        r1v.y = bfmax4(za1.y, zb1.y, zc1.y, zd1.y);
        r1v.z = bfmax4(za1.z, zb1.z, zc1.z, zd1.z);
        r1v.w = bfmax4(za1.w, zb1.w, zc1.w, zd1.w);
        unsigned short* dst = Qw + p * QSTR + rem * 8;
        *(ushort4*)(dst) = r0v;
        *(ushort4*)(dst + 4) = r1v;
    }
    __syncthreads();

    // ---- conv3: octile w per wave; B from LDS ----
    {
        const unsigned short* qb = Qw + m * QSTR + 8 * bq;
        const unsigned short* wbase = W3s + (w * 6400 + lane) * 8;
        f32x4 acc = {0.f, 0.f, 0.f, 0.f};
        for (int kpos = 0; kpos < 25; ++kpos) {
            const unsigned short* qp = qb + kpos * 128;
            const unsigned short* wp = wbase + kpos * 2048;
#pragma unroll
            for (int cc = 0; cc < 4; ++cc) {
                short8 a = *(const short8*)(wp + cc * 512);
                short8 b = *(const short8*)(qp + cc * 32);
                acc = __builtin_amdgcn_mfma_f32_16x16x32_bf16(a, b, acc, 0, 0, 0);
            }
        }
        int oc = w * 16 + bq * 4;
        uint2 pk;
        pk.x = (unsigned)f2bf(lrelu(acc.x + c3b[oc])) | ((unsigned)f2bf(lrelu(acc.y + c3b[oc + 1])) << 16);
        pk.y = (unsigned)f2bf(lrelu(acc.z + c3b[oc + 2])) | ((unsigned)f2bf(lrelu(acc.w + c3b[oc + 3])) << 16);
        *(uint2*)(&h3bf[m * 136 + oc]) = pk;
    }
    __syncthreads();

    // ---- conv4: octiles {w*2, w*2+1}, K=128 ----
    {
        f32x4 acc[2] = {{0,0,0,0},{0,0,0,0}};
#pragma unroll
        for (int t = 0; t < 2; ++t) {
            const unsigned short* abase = C4Bs + ((w * 2 + t) * 4 * 64 + lane) * 8;
#pragma unroll
            for (int cc = 0; cc < 4; ++cc) {
                short8 a = *(const short8*)(abase + cc * 512);
                short8 b = *(const short8*)(&h3bf[m * 136 + cc * 32 + 8 * bq]);
                acc[t] = __builtin_amdgcn_mfma_f32_16x16x32_bf16(a, b, acc[t], 0, 0, 0);
            }
        }
#pragma unroll
        for (int t = 0; t < 2; ++t) {
            int oc = (w * 2 + t) * 16 + bq * 4;
            uint2 pk;
            pk.x = (unsigned)f2bf(lrelu(acc[t].x + c4b[oc])) | ((unsigned)f2bf(lrelu(acc[t].y + c4b[oc + 1])) << 16);
            pk.y = (unsigned)f2bf(lrelu(acc[t].z + c4b[oc + 2])) | ((unsigned)f2bf(lrelu(acc[t].w + c4b[oc + 3])) << 16);
            *(uint2*)(&h4bf[m * 264 + oc]) = pk;
        }
    }
    __syncthreads();

    // ---- conv5: octile w, K=256 ----
    {
        const unsigned short* abase = C5Bs + (w * 8 * 64 + lane) * 8;
        f32x4 acc = {0.f, 0.f, 0.f, 0.f};
#pragma unroll
        for (int cc = 0; cc < 8; ++cc) {
            short8 a = *(const short8*)(abase + cc * 512);
            short8 b = *(const short8*)(&h4bf[m * 264 + cc * 32 + 8 * bq]);
            acc = __builtin_amdgcn_mfma_f32_16x16x32_bf16(a, b, acc, 0, 0, 0);
        }
        int oc = w * 16 + bq * 4;
        uint2 pk;
        pk.x = (unsigned)f2bf(lrelu(acc.x + c5b[oc])) | ((unsigned)f2bf(lrelu(acc.y + c5b[oc + 1])) << 16);
        pk.y = (unsigned)f2bf(lrelu(acc.z + c5b[oc + 2])) | ((unsigned)f2bf(lrelu(acc.w + c5b[oc + 3])) << 16);
        *(uint2*)(&h5bf[m * 136 + oc]) = pk;
    }
    __syncthreads();

    // ---- dense: octiles w*4..w*4+3, K=128 ----
    {
        f32x4 acc[4] = {{0,0,0,0},{0,0,0,0},{0,0,0,0},{0,0,0,0}};
#pragma unroll
        for (int t = 0; t < 4; ++t) {
            const unsigned short* abase = DWBs + ((w * 4 + t) * 4 * 64 + lane) * 8;
#pragma unroll
            for (int cc = 0; cc < 4; ++cc) {
                short8 a = *(const short8*)(abase + cc * 512);
                short8 b = *(const short8*)(&h5bf[m * 136 + cc * 32 + 8 * bq]);
                acc[t] = __builtin_amdgcn_mfma_f32_16x16x32_bf16(a, b, acc[t], 0, 0, 0);
            }
        }
#pragma unroll
        for (int t = 0; t < 4; ++t) {
            int oc = (w * 4 + t) * 16 + bq * 4;
            out[(oc + 0) * 576 + n0 + m] = acc[t].x + db[oc + 0];
            out[(oc + 1) * 576 + n0 + m] = acc[t].y + db[oc + 1];
            out[(oc + 2) * 576 + n0 + m] = acc[t].z + db[oc + 2];
            out[(oc + 3) * 576 + n0 + m] = acc[t].w + db[oc + 3];
        }
    }
}

extern "C" void kernel_launch(void* const* d_in, const int* in_sizes, int n_in,
                              void* d_out, int out_size, void* d_ws, size_t ws_size,
                              hipStream_t stream) {
    const float* x   = (const float*)d_in[0];
    const float* c1w = (const float*)d_in[1];
    const float* c1b = (const float*)d_in[2];
    const float* c2w = (const float*)d_in[3];
    const float* c2b = (const float*)d_in[4];
    const float* c3w = (const float*)d_in[5];
    const float* c3b = (const float*)d_in[6];
    const float* c4w = (const float*)d_in[7];
    const float* c4b = (const float*)d_in[8];
    const float* c5w = (const float*)d_in[9];
    const float* c5b = (const float*)d_in[10];
    const float* dw  = (const float*)d_in[11];
    const float* db  = (const float*)d_in[12];
    float* out = (float*)d_out;

    float* ws = (float*)d_ws;
    unsigned*       P2u  = (unsigned*)(ws);                  // 160000 f32 slots
    unsigned short* P2   = (unsigned short*)(ws);
    unsigned short* Z2   = (unsigned short*)(ws + 160000);   // 112896
    unsigned short* W2s  = (unsigned short*)(ws + 272896);   // 204800
    unsigned short* W3s  = (unsigned short*)(ws + 477696);   // 204800
    unsigned short* C4Bs = (unsigned short*)(ws + 682496);   // 16384
    unsigned short* C5Bs = (unsigned short*)(ws + 698880);   // 16384
    unsigned short* DWBs = (unsigned short*)(ws + 715264);   // 32768

    k_front<<<256, 512, 0, stream>>>(x, c1w, c1b, c2w, c3w, c4w, c5w, dw,
                                     P2u, W2s, W3s, C4Bs, C5Bs, DWBs);
    k_conv2<<<168, 256, 0, stream>>>(P2, W2s, c2b, Z2);
    k_tail<<<36, 512, 0, stream>>>(Z2, W3s, c3b, C4Bs, c4b, C5Bs, c5b, DWBs, db, out);
}

// Round 16
// 66.900 us; speedup vs baseline: 1.6070x; 1.2310x over previous
//
#include <hip/hip_runtime.h>

#define SLOPE 0.01f

typedef __attribute__((ext_vector_type(8))) short short8;
typedef __attribute__((ext_vector_type(4))) float f32x4;

__device__ __forceinline__ float lrelu(float v) { return v >= 0.f ? v : SLOPE * v; }

__device__ __forceinline__ unsigned short f2bf(float f) {
    union { float f; unsigned int u; } v; v.f = f;
    unsigned int r = v.u + 0x7fffu + ((v.u >> 16) & 1u);
    return (unsigned short)(r >> 16);
}
__device__ __forceinline__ float bf2f(unsigned short h) {
    union { unsigned int u; float f; } v; v.u = ((unsigned int)h) << 16;
    return v.f;
}
__device__ __forceinline__ unsigned short bfmax4(unsigned short a, unsigned short b,
                                                 unsigned short c, unsigned short d) {
    float m = fmaxf(fmaxf(bf2f(a), bf2f(b)), fmaxf(bf2f(c), bf2f(d)));
    union { float f; unsigned int u; } v; v.f = m;
    return (unsigned short)(v.u >> 16);
}

// MFMA A-fragment swizzle (16-oc tiles):
//   frag for (octile t, kblock kb) at lane l = W[((t*(K/32)+kb)*64+l)*8 .. +8)
__device__ __forceinline__ int swz(int oc, int k, int Kdiv32) {
    return (((oc >> 4) * Kdiv32 + (k >> 5)) * 64 + ((k >> 3) & 3) * 16 + (oc & 15)) * 8 + (k & 7);
}

// ---------------------------------------------------------------------------
// R16 = R13 byte-exact (measured best: 67.0us). The neighborhood is probed:
// monolithic + software grid barriers (R7-R12): >=112us (barriers ~50us each
// regardless of algorithm); k_conv2@84x512 (R14): 51us latency chain (36 VGPR,
// no load pipelining); k_front@256x512 (R15): +15us (lost block-level overlap).
// ~20us phase work + ~45us launch/boundary overhead = structural floor for
// this 3-kernel decomposition.
// Workspace (f32 slot offsets):
//   P2   bf16 [4][25][25][128]   @ 0       (160000)
//   Z2   bf16 [4][21][21][128]   @ 160000  (112896)
//   W2s  bf16 swz K=3200         @ 272896  (204800)
//   W3s  bf16 swz K=3200         @ 477696  (204800)
//   C4Bs bf16 swz K=128          @ 682496  (16384)
//   C5Bs bf16 swz K=256          @ 698880  (16384)
//   DWBs bf16 swz K=128          @ 715264  (32768)
// ---------------------------------------------------------------------------

// K1: [0,1250) fused conv1+pool1 -> P2. [1250,1506) W2/W3 swizzle-transpose.
//     [1506,2018) swizzled bf16 casts of c4w/c5w/dw.
__global__ __launch_bounds__(256) void k_front(const float* __restrict__ x,
                                               const float* __restrict__ c1w,
                                               const float* __restrict__ c1b,
                                               const float* __restrict__ c2w,
                                               const float* __restrict__ c3w,
                                               const float* __restrict__ c4w,
                                               const float* __restrict__ c5w,
                                               const float* __restrict__ dw,
                                               unsigned short* __restrict__ P2,
                                               unsigned short* __restrict__ W2s,
                                               unsigned short* __restrict__ W3s,
                                               unsigned short* __restrict__ C4Bs,
                                               unsigned short* __restrict__ C5Bs,
                                               unsigned short* __restrict__ DWBs) {
    __shared__ float smem[9600];
    int bid = blockIdx.x, tid = threadIdx.x;

    if (bid < 1250) {
        for (int idx = tid; idx < 9600; idx += 256) smem[idx] = c1w[idx];
        __syncthreads();

        int t = bid * 256 + tid;          // [0, 320000)
        int ic = t & 127;
        int rest = t >> 7;
        int B = rest % 25;
        int A = (rest / 25) % 25;
        int ph = rest / 625;
        int py = ph >> 1, px = ph & 1;
        int r0 = 2 * A + py, s0 = 2 * B + px;

        float a00 = 0.f, a01 = 0.f, a10 = 0.f, a11 = 0.f;
        const float* lw = smem + ic * 75;
        for (int c = 0; c < 3; ++c) {
            const float* xc = x + c * 576;
            const float* lwc = lw + c * 25;
#pragma unroll
            for (int ky = 0; ky < 5; ++ky) {
                int iy = r0 + ky - 16;
                bool v0 = (iy >= 0) && (iy < 24);
                bool v1 = (iy + 1 >= 0) && (iy + 1 < 24);
                if (!v0 && !v1) continue;
#pragma unroll
                for (int kx = 0; kx < 5; ++kx) {
                    int ix = s0 + kx - 16;
                    float w = lwc[ky * 5 + kx];
                    bool u0 = (ix >= 0) && (ix < 24);
                    bool u1 = (ix + 1 >= 0) && (ix + 1 < 24);
                    float x00 = (v0 && u0) ? xc[iy * 24 + ix] : 0.f;
                    float x01 = (v0 && u1) ? xc[iy * 24 + ix + 1] : 0.f;
                    float x10 = (v1 && u0) ? xc[(iy + 1) * 24 + ix] : 0.f;
                    float x11 = (v1 && u1) ? xc[(iy + 1) * 24 + ix + 1] : 0.f;
                    a00 += x00 * w; a01 += x01 * w; a10 += x10 * w; a11 += x11 * w;
                }
            }
        }
        float mx = fmaxf(fmaxf(a00, a01), fmaxf(a10, a11));
        P2[t] = f2bf(lrelu(c1b[ic] + mx));
    } else if (bid < 1506) {
        int wbid = bid - 1250;            // 0..255
        int oc = wbid & 127;
        const float* src = (wbid < 128) ? (c2w + oc * 3200) : (c3w + oc * 3200);
        unsigned short* dst = (wbid < 128) ? W2s : W3s;
        for (int idx = tid; idx < 3200; idx += 256) smem[idx] = src[idx];
        __syncthreads();
        for (int idx = tid; idx < 3200; idx += 256) {
            int ic = idx & 127, kpos = idx >> 7;
            dst[swz(oc, kpos * 128 + ic, 100)] = f2bf(smem[ic * 25 + kpos]);
        }
    } else {
        int e = (bid - 1506) * 256 + tid;   // [0, 131072)
        if (e < 32768) {
            int oc = e >> 7, k = e & 127;
            C4Bs[swz(oc, k, 4)] = f2bf(c4w[e]);
        } else if (e < 65536) {
            int e2 = e - 32768;
            int oc = e2 >> 8, k = e2 & 255;
            C5Bs[swz(oc, k, 8)] = f2bf(c5w[e2]);
        } else {
            int e2 = e - 65536;
            int oc = e2 >> 7, k = e2 & 127;
            DWBs[swz(oc, k, 4)] = f2bf(dw[e2]);
        }
    }
}

// K2: conv2 via MFMA, swizzled W2 -> Z2[ph][A][B][oc]  (R13-exact, 168x256)
__global__ __launch_bounds__(256) void k_conv2(const unsigned short* __restrict__ P2,
                                               const unsigned short* __restrict__ W2s,
                                               const float* __restrict__ bias,
                                               unsigned short* __restrict__ Z2) {
    int bid = blockIdx.x;          // 168 = 4ph * 21A * 2oh
    int ph = bid / 42;
    int rem = bid % 42;
    int A = rem >> 1;
    int oh = rem & 1;
    int tid = threadIdx.x, lane = tid & 63, wid = tid >> 6;
    int m = lane & 15, bq = lane >> 4;
    int oc0 = oh * 64 + wid * 16;
    int t = oh * 4 + wid;                      // oc tile index
    const unsigned short* wbase = W2s + (t * 100 * 64 + lane) * 8;
    const unsigned short* pbase = P2 + ((ph * 25 + A) * 25) * 128 + 8 * bq;
    f32x4 acc0 = {0.f, 0.f, 0.f, 0.f}, acc1 = {0.f, 0.f, 0.f, 0.f};
    for (int kpos = 0; kpos < 25; ++kpos) {
        int ky = kpos / 5, kx = kpos % 5;
        const unsigned short* wp = wbase + kpos * 4 * 512;
        const unsigned short* p0 = pbase + (ky * 25 + m + kx) * 128;
        const unsigned short* p1 = p0 + 5 * 128;
#pragma unroll
        for (int cc = 0; cc < 4; ++cc) {
            short8 a  = *(const short8*)(wp + cc * 512);
            short8 b0 = *(const short8*)(p0 + cc * 32);
            short8 b1 = *(const short8*)(p1 + cc * 32);
            acc0 = __builtin_amdgcn_mfma_f32_16x16x32_bf16(a, b0, acc0, 0, 0, 0);
            acc1 = __builtin_amdgcn_mfma_f32_16x16x32_bf16(a, b1, acc1, 0, 0, 0);
        }
    }
    int ocb = oc0 + 4 * bq;
    float b0v = bias[ocb], b1v = bias[ocb + 1], b2v = bias[ocb + 2], b3v = bias[ocb + 3];
    unsigned short* zrow = Z2 + ((ph * 21 + A) * 21) * 128 + ocb;
    {
        ushort4 pk;
        pk.x = f2bf(lrelu(acc0.x + b0v));
        pk.y = f2bf(lrelu(acc0.y + b1v));
        pk.z = f2bf(lrelu(acc0.z + b2v));
        pk.w = f2bf(lrelu(acc0.w + b3v));
        *(ushort4*)(zrow + m * 128) = pk;          // B = m (0..15)
    }
    if (m >= 11) {                                 // B = m+5 (16..20)
        ushort4 pk;
        pk.x = f2bf(lrelu(acc1.x + b0v));
        pk.y = f2bf(lrelu(acc1.y + b1v));
        pk.z = f2bf(lrelu(acc1.z + b2v));
        pk.w = f2bf(lrelu(acc1.w + b3v));
        *(ushort4*)(zrow + (m + 5) * 128) = pk;
    }
}

// K3: pool2-gather + conv3 + conv4 + conv5 + dense (R13-exact).
// 36 blocks x 512 threads (8 waves), 16 patches per block, LDS 119.8 KB.
#define QSTR 3208
__global__ __launch_bounds__(512) void k_tail(const unsigned short* __restrict__ Z2,
                                              const unsigned short* __restrict__ W3s,
                                              const float* __restrict__ c3b,
                                              const unsigned short* __restrict__ C4Bs,
                                              const float* __restrict__ c4b,
                                              const unsigned short* __restrict__ C5Bs,
                                              const float* __restrict__ c5b,
                                              const unsigned short* __restrict__ DWBs,
                                              const float* __restrict__ db,
                                              float* __restrict__ out) {
    __shared__ unsigned short lds[59904];          // Qw | h3 | h4 | h5
    unsigned short* Qw   = lds;                    // [16][QSTR]
    unsigned short* h3bf = lds + 16 * QSTR;        // [16][136]
    unsigned short* h4bf = h3bf + 16 * 136;        // [16][264]
    unsigned short* h5bf = h4bf + 16 * 264;        // [16][136]

    int bid = blockIdx.x, tid = threadIdx.x;
    int n0 = bid * 16;
    int lane = tid & 63, w = tid >> 6;             // 8 waves
    int m = lane & 15, bq = lane >> 4;

    // ---- pool2 gather: window[p][kpos*128+ic] = max 2x2 of Z2 ----
    for (int v = tid; v < 6400; v += 512) {
        int p = v / 400;
        int rem = v - p * 400;
        int kpos = rem >> 4;
        int ic0 = (rem & 15) * 8;
        int e = kpos / 5, f = kpos % 5;
        int n = n0 + p, i = n / 24, j = n % 24;
        int ph1 = (i & 1) * 2 + (j & 1);
        int C = (i >> 2) + e, D = (j >> 2) + f;
        int r0 = 2 * C + ((i >> 1) & 1), s0 = 2 * D + ((j >> 1) & 1);
        const unsigned short* z = Z2 + ((ph1 * 21 + r0) * 21 + s0) * 128 + ic0;
        ushort4 za0 = *(const ushort4*)(z);
        ushort4 za1 = *(const ushort4*)(z + 4);
        ushort4 zb0 = *(const ushort4*)(z + 128);
        ushort4 zb1 = *(const ushort4*)(z + 132);
        ushort4 zc0 = *(const ushort4*)(z + 21 * 128);
        ushort4 zc1 = *(const ushort4*)(z + 21 * 128 + 4);
        ushort4 zd0 = *(const ushort4*)(z + 22 * 128);
        ushort4 zd1 = *(const ushort4*)(z + 22 * 128 + 4);
        ushort4 r0v, r1v;
        r0v.x = bfmax4(za0.x, zb0.x, zc0.x, zd0.x);
        r0v.y = bfmax4(za0.y, zb0.y, zc0.y, zd0.y);
        r0v.z = bfmax4(za0.z, zb0.z, zc0.z, zd0.z);
        r0v.w = bfmax4(za0.w, zb0.w, zc0.w, zd0.w);
        r1v.x = bfmax4(za1.x, zb1.x, zc1.x, zd1.x);
        r1v.y = bfmax4(za1.y, zb1.y, zc1.y, zd1.y);
        r1v.z = bfmax4(za1.z, zb1.z, zc1.z, zd1.z);
        r1v.w = bfmax4(za1.w, zb1.w, zc1.w, zd1.w);
        unsigned short* dst = Qw + p * QSTR + rem * 8;
        *(ushort4*)(dst) = r0v;
        *(ushort4*)(dst + 4) = r1v;
    }
    __syncthreads();

    // ---- conv3: octile w per wave; B from LDS ----
    {
        const unsigned short* qb = Qw + m * QSTR + 8 * bq;
        const unsigned short* wbase = W3s + (w * 6400 + lane) * 8;
        f32x4 acc = {0.f, 0.f, 0.f, 0.f};
        for (int kpos = 0; kpos < 25; ++kpos) {
            const unsigned short* qp = qb + kpos * 128;
            const unsigned short* wp = wbase + kpos * 2048;
#pragma unroll
            for (int cc = 0; cc < 4; ++cc) {
                short8 a = *(const short8*)(wp + cc * 512);
                short8 b = *(const short8*)(qp + cc * 32);
                acc = __builtin_amdgcn_mfma_f32_16x16x32_bf16(a, b, acc, 0, 0, 0);
            }
        }
        int oc = w * 16 + bq * 4;
        uint2 pk;
        pk.x = (unsigned)f2bf(lrelu(acc.x + c3b[oc])) | ((unsigned)f2bf(lrelu(acc.y + c3b[oc + 1])) << 16);
        pk.y = (unsigned)f2bf(lrelu(acc.z + c3b[oc + 2])) | ((unsigned)f2bf(lrelu(acc.w + c3b[oc + 3])) << 16);
        *(uint2*)(&h3bf[m * 136 + oc]) = pk;
    }
    __syncthreads();

    // ---- conv4: octiles {w*2, w*2+1}, K=128 ----
    {
        f32x4 acc[2] = {{0,0,0,0},{0,0,0,0}};
#pragma unroll
        for (int t = 0; t < 2; ++t) {
            const unsigned short* abase = C4Bs + ((w * 2 + t) * 4 * 64 + lane) * 8;
#pragma unroll
            for (int cc = 0; cc < 4; ++cc) {
                short8 a = *(const short8*)(abase + cc * 512);
                short8 b = *(const short8*)(&h3bf[m * 136 + cc * 32 + 8 * bq]);
                acc[t] = __builtin_amdgcn_mfma_f32_16x16x32_bf16(a, b, acc[t], 0, 0, 0);
            }
        }
#pragma unroll
        for (int t = 0; t < 2; ++t) {
            int oc = (w * 2 + t) * 16 + bq * 4;
            uint2 pk;
            pk.x = (unsigned)f2bf(lrelu(acc[t].x + c4b[oc])) | ((unsigned)f2bf(lrelu(acc[t].y + c4b[oc + 1])) << 16);
            pk.y = (unsigned)f2bf(lrelu(acc[t].z + c4b[oc + 2])) | ((unsigned)f2bf(lrelu(acc[t].w + c4b[oc + 3])) << 16);
            *(uint2*)(&h4bf[m * 264 + oc]) = pk;
        }
    }
    __syncthreads();

    // ---- conv5: octile w, K=256 ----
    {
        const unsigned short* abase = C5Bs + (w * 8 * 64 + lane) * 8;
        f32x4 acc = {0.f, 0.f, 0.f, 0.f};
#pragma unroll
        for (int cc = 0; cc < 8; ++cc) {
            short8 a = *(const short8*)(abase + cc * 512);
            short8 b = *(const short8*)(&h4bf[m * 264 + cc * 32 + 8 * bq]);
            acc = __builtin_amdgcn_mfma_f32_16x16x32_bf16(a, b, acc, 0, 0, 0);
        }
        int oc = w * 16 + bq * 4;
        uint2 pk;
        pk.x = (unsigned)f2bf(lrelu(acc.x + c5b[oc])) | ((unsigned)f2bf(lrelu(acc.y + c5b[oc + 1])) << 16);
        pk.y = (unsigned)f2bf(lrelu(acc.z + c5b[oc + 2])) | ((unsigned)f2bf(lrelu(acc.w + c5b[oc + 3])) << 16);
        *(uint2*)(&h5bf[m * 136 + oc]) = pk;
    }
    __syncthreads();

    // ---- dense: octiles w*4..w*4+3, K=128 ----
    {
        f32x4 acc[4] = {{0,0,0,0},{0,0,0,0},{0,0,0,0},{0,0,0,0}};
#pragma unroll
        for (int t = 0; t < 4; ++t) {
            const unsigned short* abase = DWBs + ((w * 4 + t) * 4 * 64 + lane) * 8;
#pragma unroll
            for (int cc = 0; cc < 4; ++cc) {
                short8 a = *(const short8*)(abase + cc * 512);
                short8 b = *(const short8*)(&h5bf[m * 136 + cc * 32 + 8 * bq]);
                acc[t] = __builtin_amdgcn_mfma_f32_16x16x32_bf16(a, b, acc[t], 0, 0, 0);
            }
        }
#pragma unroll
        for (int t = 0; t < 4; ++t) {
            int oc = (w * 4 + t) * 16 + bq * 4;
            out[(oc + 0) * 576 + n0 + m] = acc[t].x + db[oc + 0];
            out[(oc + 1) * 576 + n0 + m] = acc[t].y + db[oc + 1];
            out[(oc + 2) * 576 + n0 + m] = acc[t].z + db[oc + 2];
            out[(oc + 3) * 576 + n0 + m] = acc[t].w + db[oc + 3];
        }
    }
}

extern "C" void kernel_launch(void* const* d_in, const int* in_sizes, int n_in,
                              void* d_out, int out_size, void* d_ws, size_t ws_size,
                              hipStream_t stream) {
    const float* x   = (const float*)d_in[0];
    const float* c1w = (const float*)d_in[1];
    const float* c1b = (const float*)d_in[2];
    const float* c2w = (const float*)d_in[3];
    const float* c2b = (const float*)d_in[4];
    const float* c3w = (const float*)d_in[5];
    const float* c3b = (const float*)d_in[6];
    const float* c4w = (const float*)d_in[7];
    const float* c4b = (const float*)d_in[8];
    const float* c5w = (const float*)d_in[9];
    const float* c5b = (const float*)d_in[10];
    const float* dw  = (const float*)d_in[11];
    const float* db  = (const float*)d_in[12];
    float* out = (float*)d_out;

    float* ws = (float*)d_ws;
    unsigned short* P2   = (unsigned short*)(ws);            // 160000 f32 slots
    unsigned short* Z2   = (unsigned short*)(ws + 160000);   // 112896
    unsigned short* W2s  = (unsigned short*)(ws + 272896);   // 204800
    unsigned short* W3s  = (unsigned short*)(ws + 477696);   // 204800
    unsigned short* C4Bs = (unsigned short*)(ws + 682496);   // 16384
    unsigned short* C5Bs = (unsigned short*)(ws + 698880);   // 16384
    unsigned short* DWBs = (unsigned short*)(ws + 715264);   // 32768

    k_front<<<2018, 256, 0, stream>>>(x, c1w, c1b, c2w, c3w, c4w, c5w, dw,
                                      P2, W2s, W3s, C4Bs, C5Bs, DWBs);
    k_conv2<<<168, 256, 0, stream>>>(P2, W2s, c2b, Z2);
    k_tail<<<36, 512, 0, stream>>>(Z2, W3s, c3b, C4Bs, c4b, C5Bs, c5b, DWBs, db, out);
}